// Round 11
// baseline (200.397 us; speedup 1.0000x reference)
//
#include <hip/hip_runtime.h>
#include <math.h>

// Problem constants (B=4, S=2048, H=1024, E=16, TOP_K=4)
constexpr int kTokens = 8192;   // B*S
constexpr int kH      = 1024;
constexpr int kE      = 16;
constexpr int kTopK   = 4;
constexpr int kNC     = 16;     // h-splits (64 h each)

typedef const float __attribute__((address_space(1))) ga_float;
typedef float __attribute__((address_space(3))) lds_float;

// ---------------------------------------------------------------------------
// Stage 1 v11: r0 geometry + global_load_lds DMA staging with a 4-buffer,
// 3-tiles-ahead counted-vmcnt pipeline (T3/T4).
//
// r10 counters: fmac 47.5us, ALL utilizations low (VALU 18%, HBM 20%, occ 40%)
// -> exposed load latency (depth-1 prefetch ~300cyc cover vs 300-900cyc
// latency; vmcnt(0) drain at every __syncthreads). r5/r7 showed deepening via
// REGISTERS spills. global_load_lds stages global->LDS with zero VGPR cost:
// 4 x [64][32] linear buffers (DMA needs linear dest), XOR swizzle folded
// into the SOURCE address (store unit qs = q ^ (row&7)); read at the matching
// swizzled unit -> same 8-lane/4-bank class as r0's proven stride-36.
// Schedule: region p = { ISSUE(p+3) -> buf[(p+3)&3]; COMPUTE(p);
// s_waitcnt vmcnt(4); s_barrier }. Writes in region p only touch a buffer
// whose past readers completed before barrier_p (lgkm waits precede uses).
// Counted waits 4/4/4/4/4/2/0 -- never drained mid-loop. Rule-18 fences
// ("memory" clobber + sched_barrier(0)) at every barrier.
// Numerics unchanged: fp32 accum per 16-h chunk, fp64 fold, fp64 cross-wave
// reduce, token-major partials store.
// ---------------------------------------------------------------------------
__global__ __launch_bounds__(256, 5)
void router_fmac(const float* __restrict__ x,   const float* __restrict__ img,
                 const float* __restrict__ txt, const float* __restrict__ aud,
                 const float* __restrict__ Wg,  const float* __restrict__ Wi,
                 const float* __restrict__ Wt,  const float* __restrict__ Wa,
                 float* __restrict__ partials)
{
    // 32 KB: 4 x [64 rows][32 floats] tile buffers (2048 floats each).
    // Epilogue reuses words 0..5119 as red[4][64][20] after a full barrier.
    __shared__ float smem[8192];

    const int t  = threadIdx.x;
    const int w  = __builtin_amdgcn_readfirstlane(t >> 6);  // wave id (SGPR)
    const int ln = t & 63;                                  // lane = token
    const int hs    = blockIdx.x & 15;   // h-split
    const int tg    = blockIdx.x >> 4;   // token group
    const int tok0  = tg * 64;
    const int hbase = hs * 64;

    const float* Xs[4] = { x,  img, txt, aud };
    const float* Ws[4] = { Wg, Wi,  Wt,  Wa  };

    // DMA staging roles: wave w stages rows w*16..w*16+15 (two 8-row instrs).
    // HW writes lane ln at wave-uniform base + ln*16B -> (row base+ln>>3,
    // unit ln&7). Source col is pre-swizzled: logical unit q = (ln&7)^(row&7),
    // so stored unit qs holds logical q = qs ^ (row&7). Row-octet sources are
    // a permutation within one 128B segment -> coalescing preserved.
    const int drow = ln >> 3;                 // 0..7 (also row&7 for both instrs)
    const int dcol = ((ln & 7) ^ drow) << 2;  // logical float col of this lane
    const size_t soff0 = (size_t)(tok0 + w * 16 + drow)     * kH + hbase + dcol;
    const size_t soff1 = (size_t)(tok0 + w * 16 + 8 + drow) * kH + hbase + dcol;

#define ISSUE(p) { \
    const float* xb_ = Xs[(p) >> 1] + ((p) & 1) * 32; \
    float* d_ = smem + (((p) & 3) << 11) + (w << 9); \
    __builtin_amdgcn_global_load_lds((ga_float*)(xb_ + soff0), \
                                     (lds_float*)(d_),       16, 0, 0); \
    __builtin_amdgcn_global_load_lds((ga_float*)(xb_ + soff1), \
                                     (lds_float*)(d_ + 256), 16, 0, 0); }

#define SYNCW(NSTR) { \
    asm volatile("s_waitcnt vmcnt(" NSTR ")" ::: "memory"); \
    __builtin_amdgcn_s_barrier(); \
    asm volatile("" ::: "memory"); \
    __builtin_amdgcn_sched_barrier(0); }

    double dacc[kE];
#pragma unroll
    for (int e = 0; e < kE; ++e) dacc[e] = 0.0;
    float facc[kE];

    // lane ln reads its 8 h (logical units w*2, w*2+1) at swizzled unit
    // qs = q ^ (ln&7); weight rows are wave-uniform -> scalar s_load path.
#define COMPUTE(p) { \
    if (((p) & 1) == 0) { _Pragma("unroll") for (int e = 0; e < kE; ++e) facc[e] = 0.f; } \
    const float* buf_  = smem + (((p) & 3) << 11) + ln * 32; \
    const float* wbase = Ws[(p) >> 1] + (size_t)(hbase + ((p) & 1) * 32 + w * 8) * kE; \
    _Pragma("unroll") for (int k4 = 0; k4 < 2; ++k4) { \
        const int qs_ = ((w << 1) + k4) ^ (ln & 7); \
        const float4 xv = *(const float4*)&buf_[qs_ << 2]; \
        _Pragma("unroll") for (int j = 0; j < 4; ++j) { \
            const float xh = (j == 0) ? xv.x : (j == 1) ? xv.y : (j == 2) ? xv.z : xv.w; \
            const float* wr = wbase + (k4 * 4 + j) * kE;   /* wave-uniform -> s_load */ \
            const float4 w0 = *(const float4*)(wr + 0); \
            const float4 w1 = *(const float4*)(wr + 4); \
            const float4 w2 = *(const float4*)(wr + 8); \
            const float4 w3 = *(const float4*)(wr + 12); \
            facc[0]  += xh * w0.x;  facc[1]  += xh * w0.y; \
            facc[2]  += xh * w0.z;  facc[3]  += xh * w0.w; \
            facc[4]  += xh * w1.x;  facc[5]  += xh * w1.y; \
            facc[6]  += xh * w1.z;  facc[7]  += xh * w1.w; \
            facc[8]  += xh * w2.x;  facc[9]  += xh * w2.y; \
            facc[10] += xh * w2.z;  facc[11] += xh * w2.w; \
            facc[12] += xh * w3.x;  facc[13] += xh * w3.y; \
            facc[14] += xh * w3.z;  facc[15] += xh * w3.w; \
        } } \
    if (((p) & 1) == 1) { _Pragma("unroll") for (int e = 0; e < kE; ++e) dacc[e] += (double)facc[e]; } }

    // ---- pipeline: 3 tiles in flight; counted vmcnt; 8 barriers total ----
    ISSUE(0);  ISSUE(1);  ISSUE(2);           // 6 outstanding
    SYNCW("4");                               // tile 0 landed (all waves)
    ISSUE(3);  COMPUTE(0);  SYNCW("4");       // region 0: tile 1 landed
    ISSUE(4);  COMPUTE(1);  SYNCW("4");       // region 1
    ISSUE(5);  COMPUTE(2);  SYNCW("4");       // region 2
    ISSUE(6);  COMPUTE(3);  SYNCW("4");       // region 3
    ISSUE(7);  COMPUTE(4);  SYNCW("4");       // region 4: tile 5 landed
               COMPUTE(5);  SYNCW("2");       // region 5: tile 6 landed
               COMPUTE(6);  SYNCW("0");       // region 6: tile 7 landed
               COMPUTE(7);                    // region 7

#undef ISSUE
#undef SYNCW
#undef COMPUTE

    // ---- epilogue: cross-wave fp64 reduce (full barriers; smem reuse) ----
    __syncthreads();
#pragma unroll
    for (int q = 0; q < 4; ++q) {
        *(float4*)&smem[(w * 64 + ln) * 20 + q * 4] =
            make_float4((float)dacc[q * 4 + 0], (float)dacc[q * 4 + 1],
                        (float)dacc[q * 4 + 2], (float)dacc[q * 4 + 3]);
    }
    __syncthreads();
    {
        const int tok = t >> 2;
        const int eq  = t & 3;
        double s0 = 0.0, s1 = 0.0, s2 = 0.0, s3 = 0.0;
#pragma unroll
        for (int ww = 0; ww < 4; ++ww) {
            const float4 v = *(const float4*)&smem[(ww * 64 + tok) * 20 + eq * 4];
            s0 += (double)v.x;  s1 += (double)v.y;
            s2 += (double)v.z;  s3 += (double)v.w;
        }
        // TOKEN-MAJOR partials [tok][chunk][e].
        *(float4*)&partials[((size_t)(tok0 + tok) * kNC + hs) * kE + eq * 4] =
            make_float4((float)s0, (float)s1, (float)s2, (float)s3);
    }
}

// ---------------------------------------------------------------------------
// Stage 2: r5/r10 topk VERBATIM (proven): 256 blocks x 32 tokens, token-major
// streaming reads, fp64 combine with hc-split halves, softmax/top-k,
// per-block expert sums.
// ---------------------------------------------------------------------------
__global__ __launch_bounds__(256)
void router_topk(const float* __restrict__ partials,
                 const float* __restrict__ bg, const float* __restrict__ bi,
                 const float* __restrict__ bt, const float* __restrict__ ba,
                 float* __restrict__ out, float* __restrict__ blocksum)
{
    __shared__ double lgs[32][2][kE + 2];
    __shared__ float  pr[32][kE + 1];

    const int t    = threadIdx.x;
    const int tq   = t >> 3;        // token 0..31
    const int eq   = (t >> 1) & 3;  // e-quad
    const int hc   = t & 1;         // chunk half (c 0..7 vs 8..15)
    const int tok0 = blockIdx.x * 32;

    double a0 = 0.0, a1 = 0.0, a2 = 0.0, a3 = 0.0;
    if (hc == 0) {  // biases added exactly once, in the low half
        a0 = (double)bg[eq*4+0] + (double)bi[eq*4+0] + (double)bt[eq*4+0] + (double)ba[eq*4+0];
        a1 = (double)bg[eq*4+1] + (double)bi[eq*4+1] + (double)bt[eq*4+1] + (double)ba[eq*4+1];
        a2 = (double)bg[eq*4+2] + (double)bi[eq*4+2] + (double)bt[eq*4+2] + (double)ba[eq*4+2];
        a3 = (double)bg[eq*4+3] + (double)bi[eq*4+3] + (double)bt[eq*4+3] + (double)ba[eq*4+3];
    }

#pragma unroll
    for (int c8 = 0; c8 < 8; ++c8) {
        const int c = hc * 8 + c8;
        const float4 v = *(const float4*)(partials +
            ((size_t)(tok0 + tq) * kNC + c) * kE + eq * 4);
        a0 += (double)v.x;  a1 += (double)v.y;  a2 += (double)v.z;  a3 += (double)v.w;
    }
    lgs[tq][hc][eq*4+0] = a0;  lgs[tq][hc][eq*4+1] = a1;
    lgs[tq][hc][eq*4+2] = a2;  lgs[tq][hc][eq*4+3] = a3;
    __syncthreads();

    if (t < 32) {
        const int tok = tok0 + t;
        double lg[kE];
#pragma unroll
        for (int e = 0; e < kE; ++e) lg[e] = lgs[t][0][e] + lgs[t][1][e];

        double mx = lg[0];
#pragma unroll
        for (int e = 1; e < kE; ++e) mx = fmax(mx, lg[e]);

        float p[kE];
        float sum = 0.f;
#pragma unroll
        for (int e = 0; e < kE; ++e) {
            p[e] = expf((float)(lg[e] - mx));
            sum += p[e];
        }
        const float inv = 1.f / sum;
#pragma unroll
        for (int e = 0; e < kE; ++e) { p[e] *= inv; pr[t][e] = p[e]; }

        // top-4, descending, ties -> smallest index (matches jax.lax.top_k)
        unsigned used = 0;
        float tp[kTopK];
        int   ti[kTopK];
        float s4 = 0.f;
#pragma unroll
        for (int k = 0; k < kTopK; ++k) {
            float best = -1.f;
            int   bidx = 0;
#pragma unroll
            for (int e = 0; e < kE; ++e) {
                if (!((used >> e) & 1u) && p[e] > best) { best = p[e]; bidx = e; }
            }
            used |= 1u << bidx;
            tp[k] = best;
            ti[k] = bidx;
            s4 += best;
        }
        const float rn = 1.f / s4;

        *(float4*)&out[(size_t)tok * kTopK] =
            make_float4((float)ti[0], (float)ti[1], (float)ti[2], (float)ti[3]);
        *(float4*)&out[(size_t)kTokens * kTopK + (size_t)tok * kTopK] =
            make_float4(tp[0] * rn, tp[1] * rn, tp[2] * rn, tp[3] * rn);
    }
    __syncthreads();

    if (t < kE) {
        float s = 0.f;
#pragma unroll
        for (int tk = 0; tk < 32; ++tk) s += pr[tk][t];
        blocksum[blockIdx.x * kE + t] = s;
    }
}

// ---------------------------------------------------------------------------
// Stage 3: r5/r10 aux VERBATIM: 256 block-partials -> mean prob per expert ->
// aux loss scalar. 256 threads x 16 coalesced loads + fp64 LDS tree.
// ---------------------------------------------------------------------------
__global__ __launch_bounds__(256)
void router_aux(const float* __restrict__ blocksum, float* __restrict__ out)
{
    __shared__ double ps[16][kE];
    __shared__ double fin[kE];
    const int t = threadIdx.x;
    {
        const int e  = t & 15;
        const int bq = t >> 4;   // 0..15
        double s = 0.0;
#pragma unroll
        for (int k = 0; k < 16; ++k)
            s += (double)blocksum[(bq * 16 + k) * kE + e];
        ps[bq][e] = s;
    }
    __syncthreads();
    if (t < kE) {
        double s = 0.0;
#pragma unroll
        for (int q = 0; q < 16; ++q) s += ps[q][t];
        fin[t] = s / (double)kTokens;
    }
    __syncthreads();
    if (t == 0) {
        double aux = 0.0;
#pragma unroll
        for (int e = 0; e < kE; ++e) aux += fin[e] * log(fin[e] * (double)kE + 1e-9);
        out[(size_t)kTokens * kTopK * 2] = (float)aux;  // element 65536
    }
}

extern "C" void kernel_launch(void* const* d_in, const int* in_sizes, int n_in,
                              void* d_out, int out_size, void* d_ws, size_t ws_size,
                              hipStream_t stream)
{
    const float* x   = (const float*)d_in[0];
    const float* img = (const float*)d_in[1];
    const float* txt = (const float*)d_in[2];
    const float* aud = (const float*)d_in[3];
    const float* Wg  = (const float*)d_in[4];
    const float* bg  = (const float*)d_in[5];
    const float* Wi  = (const float*)d_in[6];
    const float* bi  = (const float*)d_in[7];
    const float* Wt  = (const float*)d_in[8];
    const float* bt  = (const float*)d_in[9];
    const float* Wa  = (const float*)d_in[10];
    const float* ba  = (const float*)d_in[11];

    float* out      = (float*)d_out;
    float* partials = (float*)d_ws;   // [8192][16][16] fp32 = 8 MB
    float* blocksum = (float*)((char*)d_ws + (size_t)kTokens * kNC * kE * 4);  // 16 KB

    router_fmac<<<2048, 256, 0, stream>>>(x, img, txt, aud, Wg, Wi, Wt, Wa, partials);
    router_topk<<<256, 256, 0, stream>>>(partials, bg, bi, bt, ba, out, blocksum);
    router_aux<<<1, 256, 0, stream>>>(blocksum, out);
}